// Round 5
// baseline (3264.057 us; speedup 1.0000x reference)
//
#include <hip/hip_runtime.h>

#define B_ 128
#define T_ 256
#define L_ 4
#define DC_ 128
#define DW_ 128
#define H_ 256
#define V_ 6000
#define Z4_ 1024   // 4*H
#define S_ 8       // blocks per group (z-column split)
#define R_ 4       // batch rows per group
#define G_ 32      // groups = B/R
#define HC_ 32     // h-chunk per block = H/S
#define NEGF -1e30f

// d_ws layout (bytes)
#define WS_FLAGS 0                            // 256 u32 (+pad to 4096)
#define WS_VTAB  4096                         // V*L*DW f32 = 12,288,000
#define WS_NH    (WS_VTAB + V_*L_*DW_*4)      // [2][G][S][R*HC] f32 = 256 KB
#define WS_PP    (WS_NH + 2*G_*S_*R_*HC_*4)   // [2][G][S][R*DW] f32 = 1 MB

__device__ __forceinline__ float sigm(float x) { return 1.0f / (1.0f + expf(-x)); }
__device__ __forceinline__ void st_a(float* p, float v) {
  __hip_atomic_store(p, v, __ATOMIC_RELAXED, __HIP_MEMORY_SCOPE_AGENT);
}
__device__ __forceinline__ float ld_a(const float* p) {
  return __hip_atomic_load(p, __ATOMIC_RELAXED, __HIP_MEMORY_SCOPE_AGENT);
}
__device__ __forceinline__ int amax4(const float* sc) {   // first-max-wins (jnp.argmax)
  float bs = sc[0]; int bw = 0;
  if (sc[1] > bs) { bs = sc[1]; bw = 1; }
  if (sc[2] > bs) { bs = sc[2]; bw = 2; }
  if (sc[3] > bs) { bs = sc[3]; bw = 3; }
  return bw;
}
__device__ __forceinline__ float invlen(int w) {
  return (w == 0) ? 1.0f : (w == 1) ? 0.5f : (w == 2) ? (1.0f / 3.0f) : 0.25f;
}

// ------------------------------------------------------------------
// Kernel 1: vocab composition table (unchanged — verified).
// ------------------------------------------------------------------
__global__ __launch_bounds__(512) void vtab_kernel(
    const float* __restrict__ char_emb, const float* __restrict__ reset_W,
    const float* __restrict__ reset_b, const float* __restrict__ com_W,
    const float* __restrict__ com_b, float* __restrict__ Vtab)
{
  const int v = blockIdx.x;
  const int tid = threadIdx.x;
  const int w = tid >> 7;
  const int e = tid & 127;
  __shared__ float emb[DC_];
  __shared__ float ge[L_][DC_];
  if (tid < DC_) emb[tid] = char_emb[v * DC_ + tid];
  __syncthreads();
  float acc = reset_b[w * DC_ + e];
  const float* W = reset_W + (size_t)w * DC_ * DC_;
  #pragma unroll 8
  for (int k = 0; k < DC_; ++k) acc = fmaf(emb[k], W[k * DC_ + e], acc);
  ge[w][e] = sigm(acc) * emb[e];
  __syncthreads();
  float acc2 = com_b[e];
  #pragma unroll 8
  for (int k = 0; k < DC_; ++k) acc2 = fmaf(ge[w][k], com_W[k * DW_ + e], acc2);
  Vtab[((size_t)v * L_ + w) * DW_ + e] = tanhf(acc2);
}

// ------------------------------------------------------------------
// Kernel 2: distributed scan, S=8 x R=4, blk = s*32+g, 1024 thr.
//  - Kx (128x128 cols of my block) + pred_W slice cached in LDS forever.
//  - zh(tau)=Kh@nh(tau) computed once per step into a 4-deep ring ->
//    no h-matvec after argmax; hring eliminated.
//  - Only global weight stream left: Kh, 128 KB/step.
// ------------------------------------------------------------------
__global__ __launch_bounds__(1024, 4) void seq_kernel(
    const int* __restrict__ chars, const float* __restrict__ Vtab,
    const float* __restrict__ Kmat, const float* __restrict__ lstm_bias,
    const float* __restrict__ pred_W, const float* __restrict__ pred_b,
    const float* __restrict__ score_U, const float* __restrict__ bos,
    float* __restrict__ out, unsigned int* __restrict__ flags,
    float* __restrict__ nh_mb, float* __restrict__ pp_mb)
{
  const int blk = blockIdx.x;
  const int s = blk >> 5;     // 0..7 column-split index
  const int g = blk & 31;     // group (4 batch rows)
  const int tid = threadIdx.x;
  const int row0 = g * R_;

  __shared__ float KxL[DC_][128];                       // 64 KB (persistent)
  __shared__ float predWL[HC_][DW_];                    // 16 KB (persistent)
  __shared__ float ringVt[R_][4][512];                  // 32 KB
  __shared__ __align__(16) float zring[4][R_][128];     // 8 KB
  __shared__ float cring[4][R_][HC_];                   // 2 KB
  __shared__ float pring[4][R_][DW_];                   // 8 KB
  __shared__ __align__(16) float nhfull[R_][H_];        // 4 KB
  __shared__ float part8[8][R_][128];                   // 16 KB (zh / zx / pp partials)
  __shared__ __align__(16) float vtsel4[DC_][R_];       // 2 KB chosen-word, [k][r]
  __shared__ float zc[R_][128];                         // 2 KB
  __shared__ __align__(16) float nhl[R_][HC_];          // 512 B
  __shared__ float biasC[128];
  __shared__ float UL[DW_], pbL[DW_];
  __shared__ float scL[R_][L_];

  // ---- persistent LDS weight caches ----
  {
    for (int i = tid; i < DC_ * 128; i += 1024) {
      int k = i >> 7, c = i & 127;
      int colg = (c >> 5) * H_ + s * HC_ + (c & 31);
      KxL[k][c] = Kmat[(size_t)k * Z4_ + colg];
    }
    for (int i = tid; i < HC_ * DW_; i += 1024)
      predWL[i >> 7][i & 127] = pred_W[(size_t)(s * HC_ + (i >> 7)) * DW_ + (i & 127)];
    if (tid < 128) {
      int c = tid;
      biasC[c] = lstm_bias[(c >> 5) * H_ + s * HC_ + (c & 31)];
      UL[c] = score_U[c];
      pbL[c] = pred_b[c];
      ((float*)zc)[c] = bos[c];   // zc row0 = bos temp
    }
  }
  __syncthreads();

  // ---- bos step (x=bos, c0=h0=0): h1, c1, pred0, zh1 ----
  {
    const float* bosv = (const float*)zc;
    float a = lstm_bias[tid];
    #pragma unroll 8
    for (int k = 0; k < DC_; ++k) a = fmaf(bosv[k], Kmat[(size_t)k * Z4_ + tid], a);
    ((float*)part8)[tid] = a;   // zbos[1024]
  }
  __syncthreads();
  if (tid < H_) {
    const float* zb = (const float*)part8;
    float zi = zb[tid], zj = zb[H_ + tid], zo = zb[3 * H_ + tid];
    float nc = sigm(zi) * tanhf(zj);
    float nh = tanhf(nc) * sigm(zo);
    #pragma unroll
    for (int r = 0; r < R_; ++r) nhfull[r][tid] = nh;
    int hl = tid - s * HC_;
    if (hl >= 0 && hl < HC_) {
      #pragma unroll
      for (int q = 0; q < 4; ++q)
        #pragma unroll
        for (int r = 0; r < R_; ++r) cring[q][r][hl] = nc;
    }
  }
  __syncthreads();
  { // pred0 (full matvec, one-time)
    int kq = tid >> 7, e = tid & 127;
    float a = 0.0f;
    #pragma unroll 8
    for (int k = kq * 32; k < kq * 32 + 32; ++k)
      a = fmaf(nhfull[0][k], pred_W[(size_t)k * DW_ + e], a);
    __syncthreads();            // zbos fully consumed
    ((float*)part8)[tid] = a;
  }
  __syncthreads();
  if (tid < DW_) {
    float p = pbL[tid];
    #pragma unroll
    for (int kq = 0; kq < 8; ++kq) p += ((float*)part8)[kq * 128 + tid];
    p = tanhf(p);
    #pragma unroll
    for (int q = 0; q < 4; ++q)
      #pragma unroll
      for (int r = 0; r < R_; ++r) pring[q][r][tid] = p;
  }
  __syncthreads();
  { // zh1 = Kh @ h1 on my 128 cols (h1 same for all r)
    int kh = tid >> 7, c = tid & 127;
    int colg = (c >> 5) * H_ + s * HC_ + (c & 31);
    const float* Kp = Kmat + (size_t)(DC_ + kh * 32) * Z4_ + colg;
    float a = 0.0f;
    #pragma unroll 8
    for (int kk = 0; kk < 32; ++kk)
      a = fmaf(Kp[(size_t)kk * Z4_], nhfull[0][kh * 32 + kk], a);
    __syncthreads();            // pred0 partials consumed
    part8[kh][0][c] = a;
  }
  __syncthreads();
  if (tid < 128) {
    float z1 = 0.0f;
    #pragma unroll
    for (int kh = 0; kh < 8; ++kh) z1 += part8[kh][0][tid];
    #pragma unroll
    for (int q = 0; q < 4; ++q)
      #pragma unroll
      for (int r = 0; r < R_; ++r) zring[q][r][tid] = z1;
  }
  __syncthreads();

  // ---- scan ----
  for (int t = 0; t < T_; ++t) {
    const int slot = t & 3;
    const int parR = (t - 1) & 1;
    const int parW = t & 1;

    // S0: Vtab gather for char t + spin for partners' step t-1
    for (int i = tid; i < R_ * 512; i += 1024) {
      int r = i >> 9, idx = i & 511;
      int ch = chars[(row0 + r) * T_ + t];
      ringVt[r][slot][idx] = Vtab[(size_t)ch * 512 + idx];
    }
    if (t > 0 && tid < S_) {
      const unsigned tgt = (unsigned)t;
      const unsigned int* fp = &flags[tid * G_ + g];
      while (__hip_atomic_load(fp, __ATOMIC_ACQUIRE, __HIP_MEMORY_SCOPE_AGENT) < tgt)
        __builtin_amdgcn_s_sleep(1);
    }
    __syncthreads();                                     // B1

    // S1: assemble nh(t-1) + pred(t-1)
    if (t > 0) {
      {
        int r = tid >> 8, h = tid & 255, sp = h >> 5, hl = h & 31;
        nhfull[r][h] =
            ld_a(&nh_mb[(((size_t)parR * G_ + g) * S_ + sp) * (R_ * HC_) + r * HC_ + hl]);
      }
      if (tid < 512) {
        int r = tid >> 7, e = tid & 127;
        float acc = pbL[e];
        #pragma unroll
        for (int sp = 0; sp < S_; ++sp)
          acc += ld_a(&pp_mb[(((size_t)parR * G_ + g) * S_ + sp) * (R_ * DW_) + r * DW_ + e]);
        pring[(t - 1) & 3][r][e] = tanhf(acc);
      }
    }
    __syncthreads();                                     // B2

    // S2: zh(t-1) partials (global Kh stream, 128 KB) + scores (1 wave per (r,w))
    if (t > 0) {
      int kh = tid >> 7, c = tid & 127;
      int colg = (c >> 5) * H_ + s * HC_ + (c & 31);
      const float* Kp = Kmat + (size_t)(DC_ + kh * 32) * Z4_ + colg;
      float a[R_] = {0.f, 0.f, 0.f, 0.f};
      #pragma unroll
      for (int q = 0; q < 8; ++q) {
        float w0 = Kp[(size_t)(q * 4 + 0) * Z4_];
        float w1 = Kp[(size_t)(q * 4 + 1) * Z4_];
        float w2 = Kp[(size_t)(q * 4 + 2) * Z4_];
        float w3 = Kp[(size_t)(q * 4 + 3) * Z4_];
        #pragma unroll
        for (int r = 0; r < R_; ++r) {
          float4 nv = *(const float4*)&nhfull[r][kh * 32 + q * 4];
          a[r] = fmaf(w0, nv.x, fmaf(w1, nv.y, fmaf(w2, nv.z, fmaf(w3, nv.w, a[r]))));
        }
      }
      #pragma unroll
      for (int r = 0; r < R_; ++r) part8[kh][r][c] = a[r];
    }
    { // scores
      int wv = tid >> 6, r = wv >> 2, w = wv & 3, l = tid & 63;
      int ps = (t - 1 - w) & 3;
      const float il = invlen(w);
      float pv = 0.0f;
      #pragma unroll
      for (int half = 0; half < 2; ++half) {
        int e = l + half * 64;
        float we = 0.0f;
        #pragma unroll
        for (int c2 = 0; c2 < L_; ++c2)
          if (c2 <= w) we += ringVt[r][(t - c2) & 3][w * DW_ + e];
        pv = fmaf(pring[ps][r][e] + UL[e], we * il, pv);
      }
      #pragma unroll
      for (int off = 32; off; off >>= 1) pv += __shfl_down(pv, off);
      if (l == 0) scL[r][w] = (w <= t) ? pv : NEGF;
    }
    __syncthreads();                                     // B3

    // S3: zh reduce -> zring[(t-1)&3]; vtsel build; outputs
    if (tid < 512) {
      if (t > 0) {
        int r = tid >> 7, c = tid & 127;
        float z = 0.0f;
        #pragma unroll
        for (int kh = 0; kh < 8; ++kh) z += part8[kh][r][c];
        zring[(t - 1) & 3][r][c] = z;
      }
      if (s == 0 && tid < R_) {
        int bw = amax4(&scL[tid][0]);
        out[(row0 + tid) * T_ + t] = scL[tid][bw];
        out[B_ * T_ + (row0 + tid) * T_ + t] = (float)(bw + 1);
      }
    } else {
      int i = tid - 512, k = i >> 2, r = i & 3;
      int bw = amax4(&scL[r][0]);
      float v = 0.0f;
      #pragma unroll
      for (int c2 = 0; c2 < L_; ++c2)
        if (c2 <= bw) v += ringVt[r][(t - c2) & 3][bw * DW_ + k];
      vtsel4[k][r] = v * invlen(bw);
    }
    __syncthreads();                                     // B4

    // S4: zx partials from LDS-cached Kx
    {
      int kh = tid >> 7, c = tid & 127;
      float a0 = 0.f, a1 = 0.f, a2 = 0.f, a3 = 0.f;
      #pragma unroll
      for (int kk = kh * 16; kk < kh * 16 + 16; ++kk) {
        float wt = KxL[kk][c];
        float4 vv = *(const float4*)&vtsel4[kk][0];
        a0 = fmaf(wt, vv.x, a0); a1 = fmaf(wt, vv.y, a1);
        a2 = fmaf(wt, vv.z, a2); a3 = fmaf(wt, vv.w, a3);
      }
      part8[kh][0][c] = a0; part8[kh][1][c] = a1;
      part8[kh][2][c] = a2; part8[kh][3][c] = a3;
    }
    __syncthreads();                                     // B5

    // S5: z full -> zc
    if (tid < 512) {
      int r = tid >> 7, c = tid & 127;
      int bw = amax4(&scL[r][0]);
      float z = biasC[c] + zring[(t - 1 - bw) & 3][r][c];
      #pragma unroll
      for (int kh = 0; kh < 8; ++kh) z += part8[kh][r][c];
      zc[r][c] = z;
    }
    __syncthreads();                                     // B6

    // S6: gates -> nc, nh; publish nh chunk
    if (tid < R_ * HC_) {
      int r = tid >> 5, hl = tid & 31;
      int bw = amax4(&scL[r][0]);
      float zi = zc[r][hl], zj = zc[r][32 + hl], zf = zc[r][64 + hl], zo = zc[r][96 + hl];
      float cp = cring[(t - 1 - bw) & 3][r][hl];
      float nc = cp * sigm(zf) + sigm(zi) * tanhf(zj);
      float nh = tanhf(nc) * sigm(zo);
      cring[slot][r][hl] = nc;
      nhl[r][hl] = nh;
      st_a(&nh_mb[(((size_t)parW * G_ + g) * S_ + s) * (R_ * HC_) + r * HC_ + hl], nh);
    }
    __syncthreads();                                     // B7

    // S7: pp partials from LDS-cached pred_W slice
    {
      int kk = tid >> 7, e = tid & 127;
      float a0 = 0.f, a1 = 0.f, a2 = 0.f, a3 = 0.f;
      #pragma unroll
      for (int h2 = kk * 4; h2 < kk * 4 + 4; ++h2) {
        float wt = predWL[h2][e];
        a0 = fmaf(wt, nhl[0][h2], a0); a1 = fmaf(wt, nhl[1][h2], a1);
        a2 = fmaf(wt, nhl[2][h2], a2); a3 = fmaf(wt, nhl[3][h2], a3);
      }
      part8[kk][0][e] = a0; part8[kk][1][e] = a1;
      part8[kk][2][e] = a2; part8[kk][3][e] = a3;
    }
    __syncthreads();                                     // B8

    // S8: pp reduce + publish, then flag
    if (tid < 512) {
      int r = tid >> 7, e = tid & 127;
      float a = 0.0f;
      #pragma unroll
      for (int kk = 0; kk < 8; ++kk) a += part8[kk][r][e];
      st_a(&pp_mb[(((size_t)parW * G_ + g) * S_ + s) * (R_ * DW_) + r * DW_ + e], a);
    }
    __syncthreads();                                     // B9 (drains mailbox stores)
    if (tid == 0)
      __hip_atomic_store(&flags[blk], (unsigned)(t + 1), __ATOMIC_RELEASE, __HIP_MEMORY_SCOPE_AGENT);
  }
}

extern "C" void kernel_launch(void* const* d_in, const int* in_sizes, int n_in,
                              void* d_out, int out_size, void* d_ws, size_t ws_size,
                              hipStream_t stream) {
  const int*   chars     = (const int*)d_in[0];
  const float* char_emb  = (const float*)d_in[1];
  const float* reset_W   = (const float*)d_in[2];
  const float* reset_b   = (const float*)d_in[3];
  const float* com_W     = (const float*)d_in[4];
  const float* com_b     = (const float*)d_in[5];
  const float* lstm_k    = (const float*)d_in[6];
  const float* lstm_bias = (const float*)d_in[7];
  const float* pred_W    = (const float*)d_in[8];
  const float* pred_b    = (const float*)d_in[9];
  const float* score_U   = (const float*)d_in[10];
  const float* bos       = (const float*)d_in[11];

  char* ws = (char*)d_ws;
  unsigned int* flags = (unsigned int*)(ws + WS_FLAGS);
  float* Vtab  = (float*)(ws + WS_VTAB);
  float* nh_mb = (float*)(ws + WS_NH);
  float* pp_mb = (float*)(ws + WS_PP);

  // d_ws is re-poisoned to 0xAA before every timed launch: flags MUST be zeroed.
  hipMemsetAsync(flags, 0, 256 * sizeof(unsigned int), stream);
  vtab_kernel<<<V_, 512, 0, stream>>>(char_emb, reset_W, reset_b, com_W, com_b, Vtab);
  seq_kernel<<<256, 1024, 0, stream>>>(chars, Vtab, lstm_k, lstm_bias, pred_W,
                                       pred_b, score_U, bos, (float*)d_out,
                                       flags, nh_mb, pp_mb);
}

// Round 6
// 2828.503 us; speedup vs baseline: 1.1540x; 1.1540x over previous
//
#include <hip/hip_runtime.h>

#define B_ 128
#define T_ 256
#define L_ 4
#define DC_ 128
#define DW_ 128
#define H_ 256
#define V_ 6000
#define Z4_ 1024   // 4*H
#define S_ 8       // blocks per group (z-column split)
#define R_ 4       // batch rows per group
#define G_ 32      // groups = B/R
#define HC_ 32     // h-chunk per block = H/S
#define NEGF -1e30f

// d_ws layout (bytes)
#define WS_FLAGS 0                            // 256 u32 (+pad to 4096)
#define WS_VTAB  4096                         // V*L*DW f32 = 12,288,000
#define WS_NH    (WS_VTAB + V_*L_*DW_*4)      // [2][G][S][R*HC] f32 = 256 KB
#define WS_PP    (WS_NH + 2*G_*S_*R_*HC_*4)   // [2][G][S][R*DW] f32 = 1 MB

__device__ __forceinline__ float sigm(float x) { return 1.0f / (1.0f + expf(-x)); }
__device__ __forceinline__ void st_a(float* p, float v) {
  __hip_atomic_store(p, v, __ATOMIC_RELAXED, __HIP_MEMORY_SCOPE_AGENT);
}
__device__ __forceinline__ float ld_a(const float* p) {
  return __hip_atomic_load(p, __ATOMIC_RELAXED, __HIP_MEMORY_SCOPE_AGENT);
}
// wave-broadcast from lane l via v_readlane (VALU pipe — avoids the LDS unit)
__device__ __forceinline__ float bcast(float v, int l) {
  return __int_as_float(__builtin_amdgcn_readlane(__float_as_int(v), l));
}
__device__ __forceinline__ int amax4(const float* sc) {   // first-max-wins (jnp.argmax)
  float bs = sc[0]; int bw = 0;
  if (sc[1] > bs) { bs = sc[1]; bw = 1; }
  if (sc[2] > bs) { bs = sc[2]; bw = 2; }
  if (sc[3] > bs) { bs = sc[3]; bw = 3; }
  return bw;
}
__device__ __forceinline__ float invlen(int w) {
  return (w == 0) ? 1.0f : (w == 1) ? 0.5f : (w == 2) ? (1.0f / 3.0f) : 0.25f;
}

// ------------------------------------------------------------------
// Kernel 1: vocab composition table (unchanged — verified).
// ------------------------------------------------------------------
__global__ __launch_bounds__(512) void vtab_kernel(
    const float* __restrict__ char_emb, const float* __restrict__ reset_W,
    const float* __restrict__ reset_b, const float* __restrict__ com_W,
    const float* __restrict__ com_b, float* __restrict__ Vtab)
{
  const int v = blockIdx.x;
  const int tid = threadIdx.x;
  const int w = tid >> 7;
  const int e = tid & 127;
  __shared__ float emb[DC_];
  __shared__ float ge[L_][DC_];
  if (tid < DC_) emb[tid] = char_emb[v * DC_ + tid];
  __syncthreads();
  float acc = reset_b[w * DC_ + e];
  const float* W = reset_W + (size_t)w * DC_ * DC_;
  #pragma unroll 8
  for (int k = 0; k < DC_; ++k) acc = fmaf(emb[k], W[k * DC_ + e], acc);
  ge[w][e] = sigm(acc) * emb[e];
  __syncthreads();
  float acc2 = com_b[e];
  #pragma unroll 8
  for (int k = 0; k < DC_; ++k) acc2 = fmaf(ge[w][k], com_W[k * DW_ + e], acc2);
  Vtab[((size_t)v * L_ + w) * DW_ + e] = tanhf(acc2);
}

// ------------------------------------------------------------------
// Kernel 2: distributed scan, S=8 x R=4, blk = s*32+g, 512 threads.
// All matvecs: weights streamed from L2 (coalesced per-lane loads),
// activations in lane registers broadcast via v_readlane -> near-zero
// LDS-unit pressure (the round-5 bottleneck). zh ring retained.
// ------------------------------------------------------------------
__global__ __launch_bounds__(512) void seq_kernel(
    const int* __restrict__ chars, const float* __restrict__ Vtab,
    const float* __restrict__ Kmat, const float* __restrict__ lstm_bias,
    const float* __restrict__ pred_W, const float* __restrict__ pred_b,
    const float* __restrict__ score_U, const float* __restrict__ bos,
    float* __restrict__ out, unsigned int* __restrict__ flags,
    float* __restrict__ nh_mb, float* __restrict__ pp_mb)
{
  const int blk = blockIdx.x;
  const int s = blk >> 5;     // 0..7 column-split index
  const int g = blk & 31;     // group (4 batch rows)
  const int tid = threadIdx.x;
  const int lane = tid & 63;
  const int row0 = g * R_;

  __shared__ float ringVt[R_][4][512];               // 32 KB
  __shared__ float pring[4][R_][DW_];                // 8 KB
  __shared__ float zring[4][R_][128];                // 8 KB (also bos z scratch)
  __shared__ float cring[4][R_][HC_];                // 2 KB
  __shared__ float part[4][R_][128];                 // 8 KB (zh/zx/pp partials)
  __shared__ __align__(16) float vtsel4[DC_][R_];    // 2 KB
  __shared__ float nhfull[R_][H_];                   // 4 KB
  __shared__ float nhl[R_][HC_];                     // 512 B
  __shared__ float h1tmp[H_];                        // 1 KB
  __shared__ int   charsL[R_][T_];                   // 4 KB
  __shared__ float biasC[128], UL[128], pbL[128];
  __shared__ float scL[R_][L_];

  // ---- one-time loads ----
  if (tid < 128) {
    biasC[tid] = lstm_bias[(tid >> 5) * H_ + s * HC_ + (tid & 31)];
    UL[tid] = score_U[tid];
    pbL[tid] = pred_b[tid];
  }
  for (int i = tid; i < R_ * T_; i += 512)
    charsL[i >> 8][i & 255] = chars[(row0 + (i >> 8)) * T_ + (i & 255)];
  for (int i = tid; i < R_ * 4 * 512; i += 512) ((float*)ringVt)[i] = 0.0f;
  __syncthreads();

  // ---- bos step (x=bos, c0=h0=0): h1/c1, pred0, zh1 ----
  float* zb = (float*)zring;   // 1024-float scratch
  for (int c2 = tid; c2 < Z4_; c2 += 512) {
    float a = lstm_bias[c2];
    #pragma unroll 8
    for (int k = 0; k < DC_; ++k) a = fmaf(bos[k], Kmat[(size_t)k * Z4_ + c2], a);
    zb[c2] = a;
  }
  __syncthreads();
  if (tid < H_) {
    float zi = zb[tid], zj = zb[H_ + tid], zo = zb[3 * H_ + tid];
    float nc = sigm(zi) * tanhf(zj);
    float nh = tanhf(nc) * sigm(zo);
    h1tmp[tid] = nh;
    int hl = tid - s * HC_;
    if (hl >= 0 && hl < HC_) {
      #pragma unroll
      for (int q = 0; q < 4; ++q)
        #pragma unroll
        for (int r = 0; r < R_; ++r) cring[q][r][hl] = nc;
    }
  }
  __syncthreads();
  { // pred0 partials (one-time full matvec)
    int kq = tid >> 7, e = tid & 127;
    float a = 0.0f;
    #pragma unroll 8
    for (int k = kq * 64; k < kq * 64 + 64; ++k)
      a = fmaf(h1tmp[k], pred_W[(size_t)k * DW_ + e], a);
    part[kq][0][e] = a;
  }
  __syncthreads();
  if (tid < 128) {
    float p = pbL[tid] + part[0][0][tid] + part[1][0][tid] + part[2][0][tid] + part[3][0][tid];
    p = tanhf(p);
    #pragma unroll
    for (int q = 0; q < 4; ++q)
      #pragma unroll
      for (int r = 0; r < R_; ++r) pring[q][r][tid] = p;
  }
  __syncthreads();
  float zh1acc;
  { // zh1 = Kh @ h1 on my 128 cols (readlane broadcast)
    int kq = tid >> 7, c = tid & 127;
    int colg = (c >> 5) * H_ + s * HC_ + (c & 31);
    const float* Kp = Kmat + (size_t)(DC_ + kq * 64) * Z4_ + colg;
    float v = h1tmp[kq * 64 + lane];
    float a = 0.0f;
    #pragma unroll
    for (int kk = 0; kk < 64; ++kk) a = fmaf(bcast(v, kk), Kp[(size_t)kk * Z4_], a);
    zh1acc = a;
  }
  __syncthreads();            // pred0 partials consumed; zb consumed
  { int kq = tid >> 7, c = tid & 127; part[kq][0][c] = zh1acc; }
  __syncthreads();
  if (tid < 128) {
    float z1 = part[0][0][tid] + part[1][0][tid] + part[2][0][tid] + part[3][0][tid];
    #pragma unroll
    for (int q = 0; q < 4; ++q)
      #pragma unroll
      for (int r = 0; r < R_; ++r) zring[q][r][tid] = z1;
  }
  __syncthreads();

  // ---- scan ----
  for (int t = 0; t < T_; ++t) {
    const int slot = t & 3;
    const int parR = (t - 1) & 1;
    const int parW = t & 1;

    // A: Vtab gather for char t; lanes 0..7 poll partners' flag(t-1)
    #pragma unroll
    for (int j = 0; j < 4; ++j) {
      int i = tid + j * 512;
      int r = i >> 9, idx = i & 511;
      ringVt[r][slot][idx] = Vtab[(size_t)charsL[r][t] * 512 + idx];
    }
    if (t > 0 && tid < S_) {
      const unsigned tgt = (unsigned)t;
      const unsigned int* fp = &flags[tid * G_ + g];
      while (__hip_atomic_load(fp, __ATOMIC_RELAXED, __HIP_MEMORY_SCOPE_AGENT) < tgt)
        __builtin_amdgcn_s_sleep(1);
    }
    __syncthreads();                                   // B1

    // B: pred(t-1) from pp partials; nh(t-1) -> LDS
    if (t > 0) {
      {
        int r = tid >> 7, e = tid & 127;
        float acc = pbL[e];
        #pragma unroll
        for (int sp = 0; sp < S_; ++sp)
          acc += ld_a(&pp_mb[(((size_t)parR * G_ + g) * S_ + sp) * (R_ * DW_) + r * DW_ + e]);
        pring[(t - 1) & 3][r][e] = tanhf(acc);
      }
      #pragma unroll
      for (int j = 0; j < 2; ++j) {
        int i = tid + j * 512;
        int r = i >> 8, kg = i & 255, sp = kg >> 5, hl = kg & 31;
        nhfull[r][kg] =
            ld_a(&nh_mb[(((size_t)parR * G_ + g) * S_ + sp) * (R_ * HC_) + r * HC_ + hl]);
      }
      __syncthreads();                                 // B2
    }

    // C: zh(t-1) partials (Kh stream + readlane) and scores
    float zha[R_];
    if (t > 0) {
      int kq = tid >> 7, c = tid & 127;
      int colg = (c >> 5) * H_ + s * HC_ + (c & 31);
      const float* Kp = Kmat + (size_t)(DC_ + kq * 64) * Z4_ + colg;
      float v0 = nhfull[0][kq * 64 + lane];
      float v1 = nhfull[1][kq * 64 + lane];
      float v2 = nhfull[2][kq * 64 + lane];
      float v3 = nhfull[3][kq * 64 + lane];
      float a0 = 0.f, a1 = 0.f, a2 = 0.f, a3 = 0.f;
      #pragma unroll
      for (int kk = 0; kk < 64; ++kk) {
        float w = Kp[(size_t)kk * Z4_];
        a0 = fmaf(bcast(v0, kk), w, a0);
        a1 = fmaf(bcast(v1, kk), w, a1);
        a2 = fmaf(bcast(v2, kk), w, a2);
        a3 = fmaf(bcast(v3, kk), w, a3);
      }
      zha[0] = a0; zha[1] = a1; zha[2] = a2; zha[3] = a3;
    }
    { // scores: 8 waves x 2 (r,w) combos
      int wv = tid >> 6, r = wv >> 1;
      #pragma unroll
      for (int ww = 0; ww < 2; ++ww) {
        int w = (wv & 1) * 2 + ww;
        int ps = (t - 1 - w) & 3;
        float il = invlen(w);
        float acc = 0.0f;
        #pragma unroll
        for (int hf = 0; hf < 2; ++hf) {
          int e = lane + hf * 64;
          float sa = 0.0f;
          #pragma unroll
          for (int c2 = 0; c2 < L_; ++c2)
            if (c2 <= w) sa += ringVt[r][(t - c2) & 3][w * 128 + e];
          acc = fmaf(pring[ps][r][e] + UL[e], sa * il, acc);
        }
        #pragma unroll
        for (int off = 32; off; off >>= 1) acc += __shfl_down(acc, off);
        if (lane == 0) scL[r][w] = (w <= t) ? acc : NEGF;
      }
    }
    if (t > 0) { int kq = tid >> 7, c = tid & 127;
      part[kq][0][c] = zha[0]; part[kq][1][c] = zha[1];
      part[kq][2][c] = zha[2]; part[kq][3][c] = zha[3]; }
    __syncthreads();                                   // B3

    // D: zring(t-1) reduce; vtsel (chosen word); outputs
    if (t > 0) {
      int rr = tid >> 7, c = tid & 127;
      zring[(t - 1) & 3][rr][c] =
          part[0][rr][c] + part[1][rr][c] + part[2][rr][c] + part[3][rr][c];
    }
    {
      int k = tid >> 2, r = tid & 3;
      int bw = amax4(scL[r]);
      float v = 0.0f;
      #pragma unroll
      for (int c2 = 0; c2 < L_; ++c2)
        if (c2 <= bw) v += ringVt[r][(t - c2) & 3][bw * 128 + k];
      vtsel4[k][r] = v * invlen(bw);
    }
    if (s == 0 && tid < R_) {
      int bw = amax4(scL[tid]);
      out[(row0 + tid) * T_ + t] = scL[tid][bw];
      out[B_ * T_ + (row0 + tid) * T_ + t] = (float)(bw + 1);
    }
    __syncthreads();                                   // B4

    // E: zx partials (Kx stream from L2 + readlane on vtsel)
    {
      int kq = tid >> 7, c = tid & 127;
      int colg = (c >> 5) * H_ + s * HC_ + (c & 31);
      const float* Kp = Kmat + (size_t)(kq * 32) * Z4_ + colg;
      float4 vv = *(const float4*)&vtsel4[kq * 32 + (lane & 31)][0];
      float a0 = 0.f, a1 = 0.f, a2 = 0.f, a3 = 0.f;
      #pragma unroll
      for (int kk = 0; kk < 32; ++kk) {
        float w = Kp[(size_t)kk * Z4_];
        a0 = fmaf(bcast(vv.x, kk), w, a0);
        a1 = fmaf(bcast(vv.y, kk), w, a1);
        a2 = fmaf(bcast(vv.z, kk), w, a2);
        a3 = fmaf(bcast(vv.w, kk), w, a3);
      }
      __syncthreads();                                 // B5 (zh partials consumed)
      part[kq][0][c] = a0; part[kq][1][c] = a1;
      part[kq][2][c] = a2; part[kq][3][c] = a3;
    }
    __syncthreads();                                   // B6

    // F: z + gates; publish nh chunk
    if (tid < R_ * HC_) {
      int r = tid >> 5, hl = tid & 31;
      int bw = amax4(scL[r]);
      int zs = (t - 1 - bw) & 3;
      float zg[4];
      #pragma unroll
      for (int gi = 0; gi < 4; ++gi) {
        int c = gi * 32 + hl;
        zg[gi] = biasC[c] + zring[zs][r][c]
               + part[0][r][c] + part[1][r][c] + part[2][r][c] + part[3][r][c];
      }
      float cp = cring[zs][r][hl];
      float nc = cp * sigm(zg[2]) + sigm(zg[0]) * tanhf(zg[1]);
      float nh = tanhf(nc) * sigm(zg[3]);
      cring[slot][r][hl] = nc;
      nhl[r][hl] = nh;
      st_a(&nh_mb[(((size_t)parW * G_ + g) * S_ + s) * (R_ * HC_) + r * HC_ + hl], nh);
    }
    __syncthreads();                                   // B7

    // G: pp partials (pred_W stream + readlane on nhl)
    {
      int hq = tid >> 7, e = tid & 127;
      const float* Wp = pred_W + (size_t)(s * HC_ + hq * 8) * DW_ + e;
      float p0 = nhl[0][lane & 31], p1 = nhl[1][lane & 31];
      float p2 = nhl[2][lane & 31], p3 = nhl[3][lane & 31];
      float a0 = 0.f, a1 = 0.f, a2 = 0.f, a3 = 0.f;
      #pragma unroll
      for (int j = 0; j < 8; ++j) {
        float w = Wp[(size_t)j * DW_];
        int li = hq * 8 + j;
        a0 = fmaf(bcast(p0, li), w, a0);
        a1 = fmaf(bcast(p1, li), w, a1);
        a2 = fmaf(bcast(p2, li), w, a2);
        a3 = fmaf(bcast(p3, li), w, a3);
      }
      part[hq][0][e] = a0; part[hq][1][e] = a1;
      part[hq][2][e] = a2; part[hq][3][e] = a3;
    }
    __syncthreads();                                   // B8

    // H: pp reduce + publish, then flag
    {
      int r = tid >> 7, e = tid & 127;
      float a = part[0][r][e] + part[1][r][e] + part[2][r][e] + part[3][r][e];
      st_a(&pp_mb[(((size_t)parW * G_ + g) * S_ + s) * (R_ * DW_) + r * DW_ + e], a);
    }
    __syncthreads();                                   // B9 (drains mailbox stores)
    if (tid == 0)
      __hip_atomic_store(&flags[blk], (unsigned)(t + 1), __ATOMIC_RELEASE, __HIP_MEMORY_SCOPE_AGENT);
  }
}

extern "C" void kernel_launch(void* const* d_in, const int* in_sizes, int n_in,
                              void* d_out, int out_size, void* d_ws, size_t ws_size,
                              hipStream_t stream) {
  const int*   chars     = (const int*)d_in[0];
  const float* char_emb  = (const float*)d_in[1];
  const float* reset_W   = (const float*)d_in[2];
  const float* reset_b   = (const float*)d_in[3];
  const float* com_W     = (const float*)d_in[4];
  const float* com_b     = (const float*)d_in[5];
  const float* lstm_k    = (const float*)d_in[6];
  const float* lstm_bias = (const float*)d_in[7];
  const float* pred_W    = (const float*)d_in[8];
  const float* pred_b    = (const float*)d_in[9];
  const float* score_U   = (const float*)d_in[10];
  const float* bos       = (const float*)d_in[11];

  char* ws = (char*)d_ws;
  unsigned int* flags = (unsigned int*)(ws + WS_FLAGS);
  float* Vtab  = (float*)(ws + WS_VTAB);
  float* nh_mb = (float*)(ws + WS_NH);
  float* pp_mb = (float*)(ws + WS_PP);

  // d_ws is re-poisoned to 0xAA before every timed launch: flags MUST be zeroed.
  hipMemsetAsync(flags, 0, 256 * sizeof(unsigned int), stream);
  vtab_kernel<<<V_, 512, 0, stream>>>(char_emb, reset_W, reset_b, com_W, com_b, Vtab);
  seq_kernel<<<256, 512, 0, stream>>>(chars, Vtab, lstm_k, lstm_bias, pred_W,
                                      pred_b, score_U, bos, (float*)d_out,
                                      flags, nh_mb, pp_mb);
}